// Round 9
// baseline (134.573 us; speedup 1.0000x reference)
//
#include <hip/hip_runtime.h>
#include <hip/hip_bf16.h>
#include <cmath>

constexpr int KN   = 8;     // spline knots
constexpr int NPAR = 23;    // 3K-1
constexpr int DD   = 32;    // DIM
constexpr float BND   = 3.0f;
constexpr float MINBW = 1e-3f;
constexpr float MIND  = 1e-3f;

#define TPB   64     // ONE wave per block (R3/R4 best)
#define ROWS  64     // batch rows per block
#define GDIMS 8      // output dims per block (4 groups cover 32) — R9
#define WST   40     // packed W row stride (shorts): 80B, 16B-aligned
#define PSTF  28     // sP row stride (floats): 112B, 2-way banks (free)
#define RECB  8192   // per-layer packed weight record bytes

typedef __attribute__((ext_vector_type(8))) short short8;      // 8 bf16 (MFMA A/B frag)
typedef __attribute__((ext_vector_type(4))) float float4v;     // MFMA C/D frag

#define RCP(x) __builtin_amdgcn_rcpf(x)

#if __has_builtin(__builtin_amdgcn_exp2f)
#define EXP2(x) __builtin_amdgcn_exp2f(x)
#else
#define EXP2(x) __expf((x) * 0.6931471805599453f)
#endif
#if __has_builtin(__builtin_amdgcn_logf)
#define LOG2F(x) __builtin_amdgcn_logf(x)
#else
#define LOG2F(x) __log2f(x)
#endif
#define MED3(x, lo, hi) __builtin_amdgcn_fmed3f((x), (lo), (hi))

constexpr float L2E = 1.4426950408889634f;   // log2(e)
constexpr float C2L = 2.0f * L2E;            // 2*log2(e), folded into W1/W2 at prep
constexpr float LN2 = 0.6931471805599453f;

__device__ __forceinline__ short f2bf(float f) {
    unsigned u = __float_as_uint(f);
    u += 0x7fffu + ((u >> 16) & 1u);     // round-to-nearest-even
    return (short)(u >> 16);
}

__device__ __forceinline__ int pkbf(float a, float b) {
    union { __hip_bfloat162 v; int i; } u;
    u.v = __float22bfloat162_rn(make_float2(a, b));
    return u.i;
}

// 4x tanh, minimum-VALU form: conditioner weights/biases are PRE-SCALED by
// 2*log2e at prep, so the MFMA output c already IS the exp2 argument:
//   tanh = 1 - 2*rcp(exp2(c) + 1)  ->  2 VALU + 2 trans per value.
// Saturates exactly at +-1 via exp2->inf/0; no clamp, no NaN path.
__device__ __forceinline__ float4v tanh4v(float4v c) {
    float4v o;
#pragma unroll
    for (int i = 0; i < 4; ++i) {
        float e = EXP2(c[i]);
        o[i] = fmaf(-2.f, RCP(e + 1.f), 1.f);
    }
    return o;
}

// Rational-quadratic spline, division-light form.
// p[0:8]=W logits, p[8:16]=H logits, p[16:23]=D logits — ALL PRE-SCALED by
// log2(e) (folded into w3/b3/p0), so every exp2 consumes them raw.
__device__ __forceinline__ float rqs_apply(float xv, const float* p, float& ldout) {
    constexpr float C1 = 2.0f * BND * MINBW;              // width floor (output space)
    constexpr float FC = 2.0f * BND * (1.0f - MINBW * KN);

    float t0w[KN], t0h[KN];
#pragma unroll
    for (int k = 0; k < KN; ++k) t0w[k] = EXP2(p[k]);
#pragma unroll
    for (int k = 0; k < KN; ++k) t0h[k] = EXP2(p[KN + k]);
    float sw = ((t0w[0] + t0w[1]) + (t0w[2] + t0w[3]))
             + ((t0w[4] + t0w[5]) + (t0w[6] + t0w[7]));
    float sh = ((t0h[0] + t0h[1]) + (t0h[2] + t0h[3]))
             + ((t0h[4] + t0h[5]) + (t0h[6] + t0h[7]));
    float r1   = RCP(sw * sh);                            // paired reciprocal
    float invw = (2.0f * BND * L2E) * (r1 * sh);          // 2B*log2e/sw
    float invh = (2.0f * BND * L2E) * (r1 * sw);
    float e2w[KN], e2h[KN];
#pragma unroll
    for (int k = 0; k < KN; ++k) e2w[k] = EXP2(t0w[k] * invw);
#pragma unroll
    for (int k = 0; k < KN; ++k) e2h[k] = EXP2(t0h[k] * invh);
    float s2w = ((e2w[0] + e2w[1]) + (e2w[2] + e2w[3]))
              + ((e2w[4] + e2w[5]) + (e2w[6] + e2w[7]));
    float s2h = ((e2h[0] + e2h[1]) + (e2h[2] + e2h[3]))
              + ((e2h[4] + e2h[5]) + (e2h[6] + e2h[7]));
    float r2   = RCP(s2w * s2h);                          // paired reciprocal
    float facw = FC * (r2 * s2h);
    float fach = FC * (r2 * s2w);

    float xc = MED3(xv, -BND, BND);

    // fused cumsum + bin search (no cw[]/ch[] arrays)
    float w0 = fmaf(facw, e2w[0], C1);
    float h0 = fmaf(fach, e2h[0], C1);
    float in_cw = -BND, in_w = w0, in_ch = -BND, in_h = h0;
    float dl0 = 0.0f, dl1 = p[2 * KN];
    bool e0 = true, e1 = false;
    float cwk = -BND + w0;                                // cw[1]
    float chk = -BND + h0;                                // ch[1]
#pragma unroll
    for (int k = 1; k < KN; ++k) {
        float wk = fmaf(facw, e2w[k], C1);
        float hk = fmaf(fach, e2h[k], C1);
        bool c = (xc >= cwk);
        in_cw = c ? cwk : in_cw;
        in_w  = c ? wk  : in_w;
        in_ch = c ? chk : in_ch;
        in_h  = c ? hk  : in_h;
        dl0   = c ? p[2 * KN + k - 1] : dl0;
        if (k < KN - 1) dl1 = c ? p[2 * KN + k] : dl1;
        if (k == 1)      e0 = !c;
        if (k == KN - 1) e1 = c;
        cwk += wk;
        chk += hk;
    }
    // last edge pinned to exactly B (reference sets cw[..,-1]=B)
    in_w = e1 ? (BND - in_cw) : in_w;
    in_h = e1 ? (BND - in_ch) : in_h;

    // fused double softplus: sp(sp(v)) = log(2 + e^v); edges pinned to 1
    // (dl pre-scaled by log2e, so exp2 direct)
    float sp0 = LOG2F(2.0f + EXP2(dl0));
    float sp1 = LOG2F(2.0f + EXP2(dl1));
    float d0 = e0 ? 1.0f : fmaf(LN2, sp0, MIND);
    float d1 = e1 ? 1.0f : fmaf(LN2, sp1, MIND);

    // division-free core: theta = u/s cleared through numerator/denominator.
    // z  = ch + h*(h u^2 + d0 u v s) / (h(u^2+v^2) + (d0+d1) u v s)
    // ld = log(h^2 * s * DN / DEN^2), DN = s(d1 u^2 + d0 v^2) + 2 h u v
    float u  = xc - in_cw;
    float v  = in_w - u;
    float s  = in_w, h = in_h;
    float uu = u * u, vv = v * v, uv = u * v;
    float uvs = uv * s;
    float t   = fmaf(v, v, uu);                 // u^2 + v^2
    float dd  = d0 + d1;
    float DEN = fmaf(h, t, dd * uvs);           // all-positive: no cancellation
    float rD  = RCP(DEN);
    float NUM = fmaf(h, uu, d0 * uvs);
    float z   = fmaf(h * NUM, rD, in_ch);
    float t2  = fmaf(d0, vv, d1 * uu);
    float DN  = fmaf(h + h, uv, t2 * s);
    float h2s = (h * h) * s;
    float larg = ((h2s * DN) * rD) * rD;

    bool inside = (xv >= -BND) && (xv <= BND);
    ldout = inside ? LN2 * LOG2F(larg) : 0.0f;
    return inside ? z : xv;
}

// C-layout -> B-frag cross-lane transpose. 8-shfl static-index variant
// (R7/R8 champion form): shuffle both channels on both static index sets,
// one 4-wide post-select.
__device__ __forceinline__ short8 xpose_h(float4v cA, float4v cB,
                                          int sl_a, int sl_b, bool qlow) {
    float4v tA = tanh4v(cA);
    float4v tB = tanh4v(cB);
    int a0 = pkbf(tA[0], tA[1]);
    int a1 = pkbf(tA[2], tA[3]);
    int b0 = pkbf(tB[0], tB[1]);
    int b1 = pkbf(tB[2], tB[3]);
    int gA0 = __shfl(a0, sl_a, 64);
    int gA1 = __shfl(a1, sl_a, 64);
    int gA2 = __shfl(a0, sl_b, 64);
    int gA3 = __shfl(a1, sl_b, 64);
    int gB0 = __shfl(b0, sl_a, 64);
    int gB1 = __shfl(b1, sl_a, 64);
    int gB2 = __shfl(b0, sl_b, 64);
    int gB3 = __shfl(b1, sl_b, 64);
    union { int4 i; short8 s; } u;
    u.i = qlow ? make_int4(gA0, gA1, gA2, gA3) : make_int4(gB0, gB1, gB2, gB3);
    return u.s;
}

__device__ __forceinline__ float4v f4v(float4 v) {
    float4v r; r[0] = v.x; r[1] = v.y; r[2] = v.z; r[3] = v.w; return r;
}

// per-lane weight/bias fragments for one layer (48 VGPRs live)
struct WFrag {
    short8 w1a, w1b, w2a, w2b, w3a, w3b;
    float4v bA1, bB1, bA2, bB2, bA3, bB3;
};

__device__ __forceinline__ WFrag load_wfrag(const char* __restrict__ wbuf,
                                            int l, int ln, int q) {
    const char* rec = wbuf + (size_t)l * RECB;
    const short* rw = (const short*)rec;
    const float* rb = (const float*)(rec + 7680);
    WFrag f;
    f.w1a = *(const short8*)&rw[ln * WST + q * 8];
    f.w1b = *(const short8*)&rw[(16 + ln) * WST + q * 8];
    f.w2a = *(const short8*)&rw[1280 + ln * WST + q * 8];
    f.w2b = *(const short8*)&rw[1280 + (16 + ln) * WST + q * 8];
    f.w3a = *(const short8*)&rw[2560 + ln * WST + q * 8];
    f.w3b = *(const short8*)&rw[2560 + (16 + ln) * WST + q * 8];
    f.bA1 = f4v(*(const float4*)&rb[4 * q]);
    f.bB1 = f4v(*(const float4*)&rb[16 + 4 * q]);
    f.bA2 = f4v(*(const float4*)&rb[32 + 4 * q]);
    f.bB2 = f4v(*(const float4*)&rb[48 + 4 * q]);
    f.bA3 = f4v(*(const float4*)&rb[64 + 4 * q]);
    f.bB3 = f4v(*(const float4*)&rb[80 + 4 * q]);
    return f;
}

// ---- prep: blocks 0..30 pack per-layer records; blocks 31..94 zero ldo ----
// W1/b1/W2/b2 pre-scaled by 2*log2e (tanh exp2 arg direct from MFMA);
// w3/b3 pre-scaled by log2(e) (spline logits consumed only via exp2).
extern "C" __global__ void __launch_bounds__(256)
k_prep(const float* __restrict__ w1, const float* __restrict__ b1,
       const float* __restrict__ w2, const float* __restrict__ b2,
       const float* __restrict__ w3, const float* __restrict__ b3,
       char* __restrict__ wbuf, float* __restrict__ ldo, int B)
{
    const int l = blockIdx.x, tid = threadIdx.x;
    if (l >= 31) {
        const int zb = l - 31;
        const int chunk = B >> 6;
        float4* dst = (float4*)(ldo + (size_t)zb * chunk);
        for (int i = tid; i < (chunk >> 2); i += 256)
            dst[i] = make_float4(0.f, 0.f, 0.f, 0.f);
        return;
    }
    short* r1 = (short*)(wbuf + (size_t)l * RECB);
    short* r2 = r1 + 1280;
    short* r3 = r2 + 1280;
    float* f1 = (float*)(wbuf + (size_t)l * RECB + 7680);
    float* f2 = f1 + 32;
    float* f3 = f2 + 32;
    const float* g1 = w1 + (size_t)l * 992;    // [31][32]
    const float* g2 = w2 + (size_t)l * 1024;   // [32][32]
    const float* g3 = w3 + (size_t)l * 736;    // [32][23]
    for (int i = tid; i < 1280; i += 256) {
        int n = i / WST, k = i - WST * n;
        r1[i] = (k < 31) ? f2bf(g1[k * 32 + n] * C2L) : (short)0;
        r2[i] = (k < 32) ? f2bf(g2[k * 32 + n] * C2L) : (short)0;
        r3[i] = (n < 23 && k < 32) ? f2bf(g3[k * 23 + n] * L2E) : (short)0;
    }
    if (tid < 32) { f1[tid] = b1[(size_t)l * 32 + tid] * C2L; f2[tid] = b2[(size_t)l * 32 + tid] * C2L; }
    if (tid < 32) f3[tid] = (tid < 23) ? b3[(size_t)l * 23 + tid] * L2E : 0.0f;
}

// Block: ONE wave, 64 rows x 8 output dims. Zero barriers; weights per-lane
// from L2; sP private; x B-frags hoisted; sP round-trip software-pipelined.
// R9: GDIMS 4->8 at TPB=64 — amortize prologue (au pack, x loads, first-WFrag
// latency) and the ldo atomic over 2x dims; weight prefetch pipeline spans
// 7 dims. (R2's GDIMS=8 regression was confounded with TPB=512; R3 proved
// TPB=64.) Grid 4096 blocks = 16/CU available vs ~8-10 resident — still
// above the residency cap, unlike GDIMS>=16.
extern "C" __global__ void __launch_bounds__(TPB, 2)
k_nsf(const float* __restrict__ x,
      const float* __restrict__ p0,
      const char* __restrict__ wbuf,
      float* __restrict__ zo, float* __restrict__ ldo, int B)
{
    __shared__ __align__(16) float sPf[ROWS * PSTF];   // spline params (f32)

    const int tid  = threadIdx.x;
    const int lane = tid & 63;
    const int q    = lane >> 4;
    const int ln   = lane & 15;
    const int qb   = q & 1;
    const bool qlow = (q < 2);
    const int sl_a = ln + 32 * qb;      // even-q source lane
    const int sl_b = sl_a + 16;         // odd-q source lane
    const int g    = blockIdx.y;
    const int ly0  = GDIMS * g;
    const long long rowbase = (long long)blockIdx.x * ROWS;
    const long long row = rowbase + tid;

    // own-row spline inputs (two float4)
    float xarr[GDIMS];
    {
        float4 xs0 = *(const float4*)(x + row * DD + ly0);
        float4 xs1 = *(const float4*)(x + row * DD + ly0 + 4);
        xarr[0] = xs0.x; xarr[1] = xs0.y; xarr[2] = xs0.z; xarr[3] = xs0.w;
        xarr[4] = xs1.x; xarr[5] = xs1.y; xarr[6] = xs1.z; xarr[7] = xs1.w;
    }

    // hoisted: x B-frags for all 4 tiles (layer-invariant)
    short8 au[4];
#pragma unroll
    for (int t = 0; t < 4; ++t) {
        const int m0 = 16 * t;
        const float4* xp = (const float4*)(x + (rowbase + m0 + ln) * DD + q * 8);
        float4 uu = xp[0], vv = xp[1];
        union { int4 i; short8 s; } c;
        c.i = make_int4(pkbf(uu.x, uu.y), pkbf(uu.z, uu.w),
                        pkbf(vv.x, vv.y), pkbf(vv.z, vv.w));
        au[t] = c.s;
    }

    float zreg[GDIMS];
    float ldacc = 0.0f;
    float pr[2][24];                    // double-buffered spline params

    // prefetch first conditioner layer's weights
    WFrag wf = load_wfrag(wbuf, (ly0 == 0) ? 0 : ly0 - 1, ln, q);

#pragma unroll
    for (int j = 0; j < GDIMS; ++j) {
        const int ly  = ly0 + j;
        const int cur = j & 1;
        WFrag wfn;
        if (ly == 0) {
            // init_param "load": fill pr[0] directly (no GEMM, no LDS)
#pragma unroll
            for (int k = 0; k < NPAR; ++k) pr[0][k] = p0[k] * L2E;
        } else {
            // ---- GEMM1 (bias folded into accumulator) ----
            float4v cA[4], cB[4];
#pragma unroll
            for (int t = 0; t < 4; ++t) {
                cA[t] = __builtin_amdgcn_mfma_f32_16x16x32_bf16(wf.w1a, au[t], wf.bA1, 0, 0, 0);
                cB[t] = __builtin_amdgcn_mfma_f32_16x16x32_bf16(wf.w1b, au[t], wf.bB1, 0, 0, 0);
            }
            short8 h1f[4];
#pragma unroll
            for (int t = 0; t < 4; ++t)
                h1f[t] = xpose_h(cA[t], cB[t], sl_a, sl_b, qlow);
            // ---- GEMM2 ----
#pragma unroll
            for (int t = 0; t < 4; ++t) {
                cA[t] = __builtin_amdgcn_mfma_f32_16x16x32_bf16(wf.w2a, h1f[t], wf.bA2, 0, 0, 0);
                cB[t] = __builtin_amdgcn_mfma_f32_16x16x32_bf16(wf.w2b, h1f[t], wf.bB2, 0, 0, 0);
            }
#pragma unroll
            for (int t = 0; t < 4; ++t)
                h1f[t] = xpose_h(cA[t], cB[t], sl_a, sl_b, qlow);
            // ---- GEMM3 ----
#pragma unroll
            for (int t = 0; t < 4; ++t) {
                cA[t] = __builtin_amdgcn_mfma_f32_16x16x32_bf16(wf.w3a, h1f[t], wf.bA3, 0, 0, 0);
                cB[t] = __builtin_amdgcn_mfma_f32_16x16x32_bf16(wf.w3b, h1f[t], wf.bB3, 0, 0, 0);
            }
            // ---- params to sP: direct f32 b128 stores ----
#pragma unroll
            for (int t = 0; t < 4; ++t) {
                const int m0 = 16 * t;
                *(float4v*)&sPf[(m0 + ln) * PSTF + 4 * q] = cA[t];
                if (qlow)
                    *(float4v*)&sPf[(m0 + ln) * PSTF + 16 + 4 * q] = cB[t];
            }

            // ---- prefetch next layer's weights (global, independent) ----
            if (j + 1 < GDIMS) wfn = load_wfrag(wbuf, ly, ln, q);

            // ---- issue own-row pr[cur] loads NOW (consumed next iter) ----
            {
                const float* pp = &sPf[tid * PSTF];
#pragma unroll
                for (int u = 0; u < 6; ++u) {
                    float4v hv = *(const float4v*)(pp + 4 * u);
                    pr[cur][4*u+0] = hv[0];
                    pr[cur][4*u+1] = hv[1];
                    pr[cur][4*u+2] = hv[2];
                    pr[cur][4*u+3] = hv[3];
                }
            }
        }

        // ---- spline for the PREVIOUS dim (its pr loaded last iter) ----
        if (j > 0) {
            float ld;
            zreg[j-1] = rqs_apply(xarr[j-1], pr[(j-1) & 1], ld);
            ldacc += ld;
        }
        if (ly != 0 && j + 1 < GDIMS) wf = wfn;
    }
    // drain: last dim's spline
    {
        float ld;
        zreg[GDIMS-1] = rqs_apply(xarr[GDIMS-1], pr[(GDIMS-1) & 1], ld);
        ldacc += ld;
    }

    float4 zv0 = make_float4(zreg[0], zreg[1], zreg[2], zreg[3]);
    float4 zv1 = make_float4(zreg[4], zreg[5], zreg[6], zreg[7]);
    *(float4*)(zo + row * DD + ly0) = zv0;
    *(float4*)(zo + row * DD + ly0 + 4) = zv1;
    unsafeAtomicAdd(&ldo[row], ldacc);
}

extern "C" void kernel_launch(void* const* d_in, const int* in_sizes, int n_in,
                              void* d_out, int out_size, void* d_ws, size_t ws_size,
                              hipStream_t stream) {
    const float* x  = (const float*)d_in[0];
    const float* p0 = (const float*)d_in[1];
    const float* w1 = (const float*)d_in[2];
    const float* b1 = (const float*)d_in[3];
    const float* w2 = (const float*)d_in[4];
    const float* b2 = (const float*)d_in[5];
    const float* w3 = (const float*)d_in[6];
    const float* b3 = (const float*)d_in[7];

    const int B = in_sizes[0] / DD;            // 65536
    float* zo  = (float*)d_out;
    float* ldo = zo + (size_t)B * DD;
    char* wbuf = (char*)d_ws;                  // 31 * 8192 B = 254 KB

    hipLaunchKernelGGL(k_prep, dim3(95), dim3(256), 0, stream,
                       w1, b1, w2, b2, w3, b3, wbuf, ldo, B);
    hipLaunchKernelGGL(k_nsf, dim3(B / ROWS, DD / GDIMS), dim3(TPB), 0, stream,
                       x, p0, wbuf, zo, ldo, B);
}

// Round 10
// 129.476 us; speedup vs baseline: 1.0394x; 1.0394x over previous
//
#include <hip/hip_runtime.h>
#include <hip/hip_bf16.h>
#include <cmath>

constexpr int KN   = 8;     // spline knots
constexpr int NPAR = 23;    // 3K-1
constexpr int DD   = 32;    // DIM
constexpr float BND   = 3.0f;
constexpr float MINBW = 1e-3f;
constexpr float MIND  = 1e-3f;

#define TPB   64     // ONE wave per block (R3/R4 best; R9 re-confirmed)
#define ROWS  64     // batch rows per block
#define GDIMS 4      // output dims per block — R9 proved 8 hits the 128-VGPR cliff
#define WST   40     // packed W row stride (shorts): 80B, 16B-aligned
#define PSTF  28     // sP row stride (floats): 112B, 2-way banks (free)
#define RECB  8192   // per-layer packed weight record bytes

typedef __attribute__((ext_vector_type(8))) short short8;      // 8 bf16 (MFMA A/B frag)
typedef __attribute__((ext_vector_type(4))) float float4v;     // MFMA C/D frag

#define RCP(x) __builtin_amdgcn_rcpf(x)

#if __has_builtin(__builtin_amdgcn_exp2f)
#define EXP2(x) __builtin_amdgcn_exp2f(x)
#else
#define EXP2(x) __expf((x) * 0.6931471805599453f)
#endif
#if __has_builtin(__builtin_amdgcn_logf)
#define LOG2F(x) __builtin_amdgcn_logf(x)
#else
#define LOG2F(x) __log2f(x)
#endif
#define MED3(x, lo, hi) __builtin_amdgcn_fmed3f((x), (lo), (hi))

constexpr float L2E = 1.4426950408889634f;   // log2(e)
constexpr float C2L = 2.0f * L2E;            // 2*log2(e), folded into W1/W2 at prep
constexpr float LN2 = 0.6931471805599453f;

__device__ __forceinline__ short f2bf(float f) {
    unsigned u = __float_as_uint(f);
    u += 0x7fffu + ((u >> 16) & 1u);     // round-to-nearest-even
    return (short)(u >> 16);
}

__device__ __forceinline__ int pkbf(float a, float b) {
    union { __hip_bfloat162 v; int i; } u;
    u.v = __float22bfloat162_rn(make_float2(a, b));
    return u.i;
}

// 4x tanh, minimum-VALU form: conditioner weights/biases are PRE-SCALED by
// 2*log2e at prep, so the MFMA output c already IS the exp2 argument:
//   tanh = 1 - 2*rcp(exp2(c) + 1)  ->  2 VALU + 2 trans per value.
// Saturates exactly at +-1 via exp2->inf/0; no clamp, no NaN path.
__device__ __forceinline__ float4v tanh4v(float4v c) {
    float4v o;
#pragma unroll
    for (int i = 0; i < 4; ++i) {
        float e = EXP2(c[i]);
        o[i] = fmaf(-2.f, RCP(e + 1.f), 1.f);
    }
    return o;
}

// Rational-quadratic spline, division-light form.
// p[0:8]=W logits, p[8:16]=H logits, p[16:23]=D logits — ALL PRE-SCALED by
// log2(e) (folded into w3/b3/p0), so every exp2 consumes them raw.
__device__ __forceinline__ float rqs_apply(float xv, const float* p, float& ldout) {
    constexpr float C1 = 2.0f * BND * MINBW;              // width floor (output space)
    constexpr float FC = 2.0f * BND * (1.0f - MINBW * KN);

    float t0w[KN], t0h[KN];
#pragma unroll
    for (int k = 0; k < KN; ++k) t0w[k] = EXP2(p[k]);
#pragma unroll
    for (int k = 0; k < KN; ++k) t0h[k] = EXP2(p[KN + k]);
    float sw = ((t0w[0] + t0w[1]) + (t0w[2] + t0w[3]))
             + ((t0w[4] + t0w[5]) + (t0w[6] + t0w[7]));
    float sh = ((t0h[0] + t0h[1]) + (t0h[2] + t0h[3]))
             + ((t0h[4] + t0h[5]) + (t0h[6] + t0h[7]));
    float r1   = RCP(sw * sh);                            // paired reciprocal
    float invw = (2.0f * BND * L2E) * (r1 * sh);          // 2B*log2e/sw
    float invh = (2.0f * BND * L2E) * (r1 * sw);
    float e2w[KN], e2h[KN];
#pragma unroll
    for (int k = 0; k < KN; ++k) e2w[k] = EXP2(t0w[k] * invw);
#pragma unroll
    for (int k = 0; k < KN; ++k) e2h[k] = EXP2(t0h[k] * invh);
    float s2w = ((e2w[0] + e2w[1]) + (e2w[2] + e2w[3]))
              + ((e2w[4] + e2w[5]) + (e2w[6] + e2w[7]));
    float s2h = ((e2h[0] + e2h[1]) + (e2h[2] + e2h[3]))
              + ((e2h[4] + e2h[5]) + (e2h[6] + e2h[7]));
    float r2   = RCP(s2w * s2h);                          // paired reciprocal
    float facw = FC * (r2 * s2h);
    float fach = FC * (r2 * s2w);

    float xc = MED3(xv, -BND, BND);

    // fused cumsum + bin search (no cw[]/ch[] arrays)
    float w0 = fmaf(facw, e2w[0], C1);
    float h0 = fmaf(fach, e2h[0], C1);
    float in_cw = -BND, in_w = w0, in_ch = -BND, in_h = h0;
    float dl0 = 0.0f, dl1 = p[2 * KN];
    bool e0 = true, e1 = false;
    float cwk = -BND + w0;                                // cw[1]
    float chk = -BND + h0;                                // ch[1]
#pragma unroll
    for (int k = 1; k < KN; ++k) {
        float wk = fmaf(facw, e2w[k], C1);
        float hk = fmaf(fach, e2h[k], C1);
        bool c = (xc >= cwk);
        in_cw = c ? cwk : in_cw;
        in_w  = c ? wk  : in_w;
        in_ch = c ? chk : in_ch;
        in_h  = c ? hk  : in_h;
        dl0   = c ? p[2 * KN + k - 1] : dl0;
        if (k < KN - 1) dl1 = c ? p[2 * KN + k] : dl1;
        if (k == 1)      e0 = !c;
        if (k == KN - 1) e1 = c;
        cwk += wk;
        chk += hk;
    }
    // last edge pinned to exactly B (reference sets cw[..,-1]=B)
    in_w = e1 ? (BND - in_cw) : in_w;
    in_h = e1 ? (BND - in_ch) : in_h;

    // fused double softplus: sp(sp(v)) = log(2 + e^v); edges pinned to 1
    // (dl pre-scaled by log2e, so exp2 direct)
    float sp0 = LOG2F(2.0f + EXP2(dl0));
    float sp1 = LOG2F(2.0f + EXP2(dl1));
    float d0 = e0 ? 1.0f : fmaf(LN2, sp0, MIND);
    float d1 = e1 ? 1.0f : fmaf(LN2, sp1, MIND);

    // division-free core: theta = u/s cleared through numerator/denominator.
    // z  = ch + h*(h u^2 + d0 u v s) / (h(u^2+v^2) + (d0+d1) u v s)
    // ld = log(h^2 * s * DN / DEN^2), DN = s(d1 u^2 + d0 v^2) + 2 h u v
    float u  = xc - in_cw;
    float v  = in_w - u;
    float s  = in_w, h = in_h;
    float uu = u * u, vv = v * v, uv = u * v;
    float uvs = uv * s;
    float t   = fmaf(v, v, uu);                 // u^2 + v^2
    float dd  = d0 + d1;
    float DEN = fmaf(h, t, dd * uvs);           // all-positive: no cancellation
    float rD  = RCP(DEN);
    float NUM = fmaf(h, uu, d0 * uvs);
    float z   = fmaf(h * NUM, rD, in_ch);
    float t2  = fmaf(d0, vv, d1 * uu);
    float DN  = fmaf(h + h, uv, t2 * s);
    float h2s = (h * h) * s;
    float larg = ((h2s * DN) * rD) * rD;

    bool inside = (xv >= -BND) && (xv <= BND);
    ldout = inside ? LN2 * LOG2F(larg) : 0.0f;
    return inside ? z : xv;
}

// C-layout -> B-frag cross-lane transpose. 8-shfl static-index variant
// (R7/R8 champion form): shuffle both channels on both static index sets,
// one 4-wide post-select.
__device__ __forceinline__ short8 xpose_h(float4v cA, float4v cB,
                                          int sl_a, int sl_b, bool qlow) {
    float4v tA = tanh4v(cA);
    float4v tB = tanh4v(cB);
    int a0 = pkbf(tA[0], tA[1]);
    int a1 = pkbf(tA[2], tA[3]);
    int b0 = pkbf(tB[0], tB[1]);
    int b1 = pkbf(tB[2], tB[3]);
    int gA0 = __shfl(a0, sl_a, 64);
    int gA1 = __shfl(a1, sl_a, 64);
    int gA2 = __shfl(a0, sl_b, 64);
    int gA3 = __shfl(a1, sl_b, 64);
    int gB0 = __shfl(b0, sl_a, 64);
    int gB1 = __shfl(b1, sl_a, 64);
    int gB2 = __shfl(b0, sl_b, 64);
    int gB3 = __shfl(b1, sl_b, 64);
    union { int4 i; short8 s; } u;
    u.i = qlow ? make_int4(gA0, gA1, gA2, gA3) : make_int4(gB0, gB1, gB2, gB3);
    return u.s;
}

__device__ __forceinline__ float4v f4v(float4 v) {
    float4v r; r[0] = v.x; r[1] = v.y; r[2] = v.z; r[3] = v.w; return r;
}

// per-lane weight/bias fragments for one layer (48 VGPRs live)
struct WFrag {
    short8 w1a, w1b, w2a, w2b, w3a, w3b;
    float4v bA1, bB1, bA2, bB2, bA3, bB3;
};

__device__ __forceinline__ WFrag load_wfrag(const char* __restrict__ wbuf,
                                            int l, int ln, int q) {
    const char* rec = wbuf + (size_t)l * RECB;
    const short* rw = (const short*)rec;
    const float* rb = (const float*)(rec + 7680);
    WFrag f;
    f.w1a = *(const short8*)&rw[ln * WST + q * 8];
    f.w1b = *(const short8*)&rw[(16 + ln) * WST + q * 8];
    f.w2a = *(const short8*)&rw[1280 + ln * WST + q * 8];
    f.w2b = *(const short8*)&rw[1280 + (16 + ln) * WST + q * 8];
    f.w3a = *(const short8*)&rw[2560 + ln * WST + q * 8];
    f.w3b = *(const short8*)&rw[2560 + (16 + ln) * WST + q * 8];
    f.bA1 = f4v(*(const float4*)&rb[4 * q]);
    f.bB1 = f4v(*(const float4*)&rb[16 + 4 * q]);
    f.bA2 = f4v(*(const float4*)&rb[32 + 4 * q]);
    f.bB2 = f4v(*(const float4*)&rb[48 + 4 * q]);
    f.bA3 = f4v(*(const float4*)&rb[64 + 4 * q]);
    f.bB3 = f4v(*(const float4*)&rb[80 + 4 * q]);
    return f;
}

// ---- prep: blocks 0..30 pack per-layer records; blocks 31..94 zero ldo ----
// W1/b1/W2/b2 pre-scaled by 2*log2e (tanh exp2 arg direct from MFMA);
// w3/b3 pre-scaled by log2(e) (spline logits consumed only via exp2).
extern "C" __global__ void __launch_bounds__(256)
k_prep(const float* __restrict__ w1, const float* __restrict__ b1,
       const float* __restrict__ w2, const float* __restrict__ b2,
       const float* __restrict__ w3, const float* __restrict__ b3,
       char* __restrict__ wbuf, float* __restrict__ ldo, int B)
{
    const int l = blockIdx.x, tid = threadIdx.x;
    if (l >= 31) {
        const int zb = l - 31;
        const int chunk = B >> 6;
        float4* dst = (float4*)(ldo + (size_t)zb * chunk);
        for (int i = tid; i < (chunk >> 2); i += 256)
            dst[i] = make_float4(0.f, 0.f, 0.f, 0.f);
        return;
    }
    short* r1 = (short*)(wbuf + (size_t)l * RECB);
    short* r2 = r1 + 1280;
    short* r3 = r2 + 1280;
    float* f1 = (float*)(wbuf + (size_t)l * RECB + 7680);
    float* f2 = f1 + 32;
    float* f3 = f2 + 32;
    const float* g1 = w1 + (size_t)l * 992;    // [31][32]
    const float* g2 = w2 + (size_t)l * 1024;   // [32][32]
    const float* g3 = w3 + (size_t)l * 736;    // [32][23]
    for (int i = tid; i < 1280; i += 256) {
        int n = i / WST, k = i - WST * n;
        r1[i] = (k < 31) ? f2bf(g1[k * 32 + n] * C2L) : (short)0;
        r2[i] = (k < 32) ? f2bf(g2[k * 32 + n] * C2L) : (short)0;
        r3[i] = (n < 23 && k < 32) ? f2bf(g3[k * 23 + n] * L2E) : (short)0;
    }
    if (tid < 32) { f1[tid] = b1[(size_t)l * 32 + tid] * C2L; f2[tid] = b2[(size_t)l * 32 + tid] * C2L; }
    if (tid < 32) f3[tid] = (tid < 23) ? b3[(size_t)l * 23 + tid] * L2E : 0.0f;
}

// Block: ONE wave, 64 rows x 4 output dims. Zero barriers; weights per-lane
// from L2; sP private; x B-frags hoisted; sP round-trip software-pipelined.
// R10: exact R8 champion restore. R9 (GDIMS=8) hit the 128-VGPR allocation
// step -> waves/SIMD 6->4 -> +3.5us. GDIMS=4 @ VGPR=84 is the sweet spot.
// Model: issue-slot-bound; trans execution overlaps VALU (R6/R7 evidence),
// so keep trans-heavy / VALU-light forms everywhere.
extern "C" __global__ void __launch_bounds__(TPB, 2)
k_nsf(const float* __restrict__ x,
      const float* __restrict__ p0,
      const char* __restrict__ wbuf,
      float* __restrict__ zo, float* __restrict__ ldo, int B)
{
    __shared__ __align__(16) float sPf[ROWS * PSTF];   // spline params (f32)

    const int tid  = threadIdx.x;
    const int lane = tid & 63;
    const int q    = lane >> 4;
    const int ln   = lane & 15;
    const int qb   = q & 1;
    const bool qlow = (q < 2);
    const int sl_a = ln + 32 * qb;      // even-q source lane
    const int sl_b = sl_a + 16;         // odd-q source lane
    const int g    = blockIdx.y;
    const int ly0  = GDIMS * g;
    const long long rowbase = (long long)blockIdx.x * ROWS;
    const long long row = rowbase + tid;

    // own-row spline inputs (one float4)
    float xarr[GDIMS];
    {
        float4 xs = *(const float4*)(x + row * DD + ly0);
        xarr[0] = xs.x; xarr[1] = xs.y; xarr[2] = xs.z; xarr[3] = xs.w;
    }

    // hoisted: x B-frags for all 4 tiles (layer-invariant)
    short8 au[4];
#pragma unroll
    for (int t = 0; t < 4; ++t) {
        const int m0 = 16 * t;
        const float4* xp = (const float4*)(x + (rowbase + m0 + ln) * DD + q * 8);
        float4 uu = xp[0], vv = xp[1];
        union { int4 i; short8 s; } c;
        c.i = make_int4(pkbf(uu.x, uu.y), pkbf(uu.z, uu.w),
                        pkbf(vv.x, vv.y), pkbf(vv.z, vv.w));
        au[t] = c.s;
    }

    float zreg[GDIMS];
    float ldacc = 0.0f;
    float pr[2][24];                    // double-buffered spline params

    // prefetch first conditioner layer's weights
    WFrag wf = load_wfrag(wbuf, (ly0 == 0) ? 0 : ly0 - 1, ln, q);

#pragma unroll
    for (int j = 0; j < GDIMS; ++j) {
        const int ly  = ly0 + j;
        const int cur = j & 1;
        WFrag wfn;
        if (ly == 0) {
            // init_param "load": fill pr[0] directly (no GEMM, no LDS)
#pragma unroll
            for (int k = 0; k < NPAR; ++k) pr[0][k] = p0[k] * L2E;
        } else {
            // ---- GEMM1 (bias folded into accumulator) ----
            float4v cA[4], cB[4];
#pragma unroll
            for (int t = 0; t < 4; ++t) {
                cA[t] = __builtin_amdgcn_mfma_f32_16x16x32_bf16(wf.w1a, au[t], wf.bA1, 0, 0, 0);
                cB[t] = __builtin_amdgcn_mfma_f32_16x16x32_bf16(wf.w1b, au[t], wf.bB1, 0, 0, 0);
            }
            short8 h1f[4];
#pragma unroll
            for (int t = 0; t < 4; ++t)
                h1f[t] = xpose_h(cA[t], cB[t], sl_a, sl_b, qlow);
            // ---- GEMM2 ----
#pragma unroll
            for (int t = 0; t < 4; ++t) {
                cA[t] = __builtin_amdgcn_mfma_f32_16x16x32_bf16(wf.w2a, h1f[t], wf.bA2, 0, 0, 0);
                cB[t] = __builtin_amdgcn_mfma_f32_16x16x32_bf16(wf.w2b, h1f[t], wf.bB2, 0, 0, 0);
            }
#pragma unroll
            for (int t = 0; t < 4; ++t)
                h1f[t] = xpose_h(cA[t], cB[t], sl_a, sl_b, qlow);
            // ---- GEMM3 ----
#pragma unroll
            for (int t = 0; t < 4; ++t) {
                cA[t] = __builtin_amdgcn_mfma_f32_16x16x32_bf16(wf.w3a, h1f[t], wf.bA3, 0, 0, 0);
                cB[t] = __builtin_amdgcn_mfma_f32_16x16x32_bf16(wf.w3b, h1f[t], wf.bB3, 0, 0, 0);
            }
            // ---- params to sP: direct f32 b128 stores ----
#pragma unroll
            for (int t = 0; t < 4; ++t) {
                const int m0 = 16 * t;
                *(float4v*)&sPf[(m0 + ln) * PSTF + 4 * q] = cA[t];
                if (qlow)
                    *(float4v*)&sPf[(m0 + ln) * PSTF + 16 + 4 * q] = cB[t];
            }

            // ---- prefetch next layer's weights (global, independent) ----
            if (j + 1 < GDIMS) wfn = load_wfrag(wbuf, ly, ln, q);

            // ---- issue own-row pr[cur] loads NOW (consumed next iter) ----
            {
                const float* pp = &sPf[tid * PSTF];
#pragma unroll
                for (int u = 0; u < 6; ++u) {
                    float4v hv = *(const float4v*)(pp + 4 * u);
                    pr[cur][4*u+0] = hv[0];
                    pr[cur][4*u+1] = hv[1];
                    pr[cur][4*u+2] = hv[2];
                    pr[cur][4*u+3] = hv[3];
                }
            }
        }

        // ---- spline for the PREVIOUS dim (its pr loaded last iter) ----
        if (j > 0) {
            float ld;
            zreg[j-1] = rqs_apply(xarr[j-1], pr[(j-1) & 1], ld);
            ldacc += ld;
        }
        if (ly != 0 && j + 1 < GDIMS) wf = wfn;
    }
    // drain: last dim's spline
    {
        float ld;
        zreg[GDIMS-1] = rqs_apply(xarr[GDIMS-1], pr[(GDIMS-1) & 1], ld);
        ldacc += ld;
    }

    float4 zv = make_float4(zreg[0], zreg[1], zreg[2], zreg[3]);
    *(float4*)(zo + row * DD + ly0) = zv;
    unsafeAtomicAdd(&ldo[row], ldacc);
}

extern "C" void kernel_launch(void* const* d_in, const int* in_sizes, int n_in,
                              void* d_out, int out_size, void* d_ws, size_t ws_size,
                              hipStream_t stream) {
    const float* x  = (const float*)d_in[0];
    const float* p0 = (const float*)d_in[1];
    const float* w1 = (const float*)d_in[2];
    const float* b1 = (const float*)d_in[3];
    const float* w2 = (const float*)d_in[4];
    const float* b2 = (const float*)d_in[5];
    const float* w3 = (const float*)d_in[6];
    const float* b3 = (const float*)d_in[7];

    const int B = in_sizes[0] / DD;            // 65536
    float* zo  = (float*)d_out;
    float* ldo = zo + (size_t)B * DD;
    char* wbuf = (char*)d_ws;                  // 31 * 8192 B = 254 KB

    hipLaunchKernelGGL(k_prep, dim3(95), dim3(256), 0, stream,
                       w1, b1, w2, b2, w3, b3, wbuf, ldo, B);
    hipLaunchKernelGGL(k_nsf, dim3(B / ROWS, DD / GDIMS), dim3(TPB), 0, stream,
                       x, p0, wbuf, zo, ldo, B);
}